// Round 3
// baseline (151.186 us; speedup 1.0000x reference)
//
#include <hip/hip_runtime.h>
#include <hip/hip_bf16.h>
#include <math.h>

#define NPTS 131072
#define DIM 32
#define MCL 256
#define KSTEPS 33          // 32 xx-steps + 1 linear (-2Ac) step
#define BPTS 256           // points per block
#define THREADS 512

typedef __attribute__((ext_vector_type(8))) short s8v;    // 8 bf16 bit-patterns
typedef __attribute__((ext_vector_type(4))) float f32x4;

__device__ __forceinline__ unsigned short f2bf(float f) {
    union { float f; unsigned u; } v; v.f = f;
    unsigned r = v.u + 0x7fffu + ((v.u >> 16) & 1u);   // RNE
    return (unsigned short)(r >> 16);
}

// async global->LDS, 16B per lane; LDS dest = uniform base + lane*16
__device__ __forceinline__ void glds16(const void* g, void* l) {
    __builtin_amdgcn_global_load_lds(
        (const __attribute__((address_space(1))) unsigned int*)g,
        (__attribute__((address_space(3))) unsigned int*)l, 16, 0, 0);
}

// ---------------------------------------------------------------------------
// prep (unchanged, proven): per cluster m:
//   A = L L^T;  E = A - I  -> G rows in MFMA-fragment order (bf16)
//   G row [32*... step 32] = -2*(A c)
//   cst[m] = log|w_m| - log(sum|w|) + log|det L| - 0.5 c^T A c
// G shorts: addr = kstep*8192 + (m>>4)*512 + (kloc>>3)*128 + (m&15)*8 + (kloc&7)
// ---------------------------------------------------------------------------
__global__ __launch_bounds__(64) void gmm_prep(
    const float* __restrict__ center,
    const float* __restrict__ L,
    const float* __restrict__ weight,
    short* __restrict__ G,
    float* __restrict__ cst)
{
    const int m = blockIdx.x;
    const int t = threadIdx.x;
    __shared__ float Ls[DIM][DIM + 1];
    __shared__ float As[DIM][DIM + 1];
    __shared__ float red[DIM];
    __shared__ int pivsh;

    const float* Lm = L + m * DIM * DIM;
    for (int k = t; k < DIM * DIM; k += 64)
        Ls[k >> 5][k & 31] = Lm[k];
    __syncthreads();

    for (int idx = t; idx < DIM * DIM; idx += 64) {
        const int j = idx >> 5, l = idx & 31;
        float a = 0.f;
        for (int d = 0; d < DIM; ++d) a = fmaf(Ls[j][d], Ls[l][d], a);
        As[j][l] = a;
    }
    __syncthreads();

    const int mt = m >> 4, ml = m & 15;
    for (int idx = t; idx < DIM * DIM; idx += 64) {
        const int j = idx >> 5, l = idx & 31;
        const float e = As[j][l] - (j == l ? 1.f : 0.f);
        G[j * 8192 + mt * 512 + (l >> 3) * 128 + ml * 8 + (l & 7)] = (short)f2bf(e);
    }
    if (t < DIM) {
        float a = 0.f;
        for (int l = 0; l < DIM; ++l) a = fmaf(As[t][l], center[m * DIM + l], a);
        G[32 * 8192 + mt * 512 + (t >> 3) * 128 + ml * 8 + (t & 7)] = (short)f2bf(-2.f * a);
        red[t] = a * center[m * DIM + t];
    }
    __syncthreads();

    float logdet = 0.f;
    for (int k = 0; k < DIM; ++k) {
        if (t == 0) {
            int piv = k;
            float best = fabsf(Ls[k][k]);
            for (int r = k + 1; r < DIM; ++r) {
                const float v = fabsf(Ls[r][k]);
                if (v > best) { best = v; piv = r; }
            }
            pivsh = piv;
        }
        __syncthreads();
        const int piv = pivsh;
        if (piv != k && t < DIM) {
            const float tmp = Ls[k][t]; Ls[k][t] = Ls[piv][t]; Ls[piv][t] = tmp;
        }
        __syncthreads();
        const float pv = Ls[k][k];
        logdet += logf(fabsf(pv));
        if (t > k && t < DIM) {
            const float f = Ls[t][k] / pv;
            for (int j = k; j < DIM; ++j) Ls[t][j] -= f * Ls[k][j];
        }
        __syncthreads();
    }

    if (t == 0) {
        float wsum = 0.f;
        for (int j = 0; j < MCL; ++j) wsum += fabsf(weight[j]);
        float t3 = 0.f;
        for (int j = 0; j < DIM; ++j) t3 += red[j];
        cst[m] = logf(fabsf(weight[m])) - logf(wsum) + logdet - 0.5f * t3;
    }
}

// ---------------------------------------------------------------------------
// main: block = 256 pts x 256 cl, 8 waves, wave tile 64x128, K = 33*32.
// A-fragments generated IN REGISTERS (xs broadcast from LDS * resident xk),
// B staged via async global_load_lds (double-buffered), ONE barrier per step.
// ---------------------------------------------------------------------------
__global__ __launch_bounds__(THREADS, 2) void gmm_mfma(
    const float* __restrict__ X,
    const short* __restrict__ G,
    const float* __restrict__ cstw,
    const float* __restrict__ thr,
    float* __restrict__ out)
{
    __shared__ __attribute__((aligned(16))) short Bb[2][8192];   // 2 x 16 KB
    __shared__ float Xs[BPTS * 33];                              // stride 33: conflict-free
    __shared__ float nrm_s[BPTS];
    __shared__ float cst_s[MCL];
    __shared__ float lse_m[BPTS];
    __shared__ float lse_d[BPTS];

    const int tid  = threadIdx.x;
    const int lane = tid & 63;
    const int w    = tid >> 6;     // wave 0..7
    const int wr   = w & 3;        // row group: 64 points
    const int wc   = w >> 2;       // col group: 128 clusters
    const int r    = lane & 15;
    const int kg   = lane >> 4;    // k-group 0..3
    const int P0   = blockIdx.x * BPTS;

    // ---- prologue: async-stage B[0], stage X into LDS, row norms
    glds16(G + (size_t)w * 1024 + lane * 8, &Bb[0][w * 1024]);
    glds16(G + (size_t)w * 1024 + 512 + lane * 8, &Bb[0][w * 1024 + 512]);

    const int p  = tid >> 1;       // 0..255
    const int hf = tid & 1;
    {
        const float4* Xg = reinterpret_cast<const float4*>(X + (size_t)(P0 + p) * DIM + hf * 16);
        float part = 0.f;
        #pragma unroll
        for (int q = 0; q < 4; ++q) {
            const float4 v = Xg[q];
            const int kb = hf * 16 + 4 * q;
            Xs[p * 33 + kb + 0] = v.x; Xs[p * 33 + kb + 1] = v.y;
            Xs[p * 33 + kb + 2] = v.z; Xs[p * 33 + kb + 3] = v.w;
            part = fmaf(v.x, v.x, part); part = fmaf(v.y, v.y, part);
            part = fmaf(v.z, v.z, part); part = fmaf(v.w, v.w, part);
        }
        part += __shfl_xor(part, 1, 64);
        if (!hf) nrm_s[p] = part;
        if (tid < MCL) cst_s[tid] = cstw[tid];
    }
    __syncthreads();   // Xs ready; B[0] landed (vmcnt drained before barrier)

    // ---- per-lane resident x-slices: xk[i][e] = X[pt(i)][kg*8+e]
    int xrow[4];
    float xk[4][8];
    #pragma unroll
    for (int i = 0; i < 4; ++i) {
        xrow[i] = (wr * 64 + i * 16 + r) * 33;
        const float* src = &Xs[xrow[i] + kg * 8];
        #pragma unroll
        for (int e = 0; e < 8; ++e) xk[i][e] = src[e];
    }

    f32x4 acc[4][8] = {};
    int buf = 0;

    for (int s = 0; s < KSTEPS; ++s) {
        // async-stage next B slice into buf^1 (in flight across the MFMA phase)
        if (s + 1 < KSTEPS) {
            const short* gs = G + (size_t)(s + 1) * 8192 + w * 1024 + lane * 8;
            glds16(gs, &Bb[buf ^ 1][w * 1024]);
            glds16(gs + 512, &Bb[buf ^ 1][w * 1024 + 512]);
        }

        // A-fragments in registers: xs broadcast * resident xk, pack bf16 pairs
        s8v af[4];
        #pragma unroll
        for (int i = 0; i < 4; ++i) {
            const float xs = (s < 32) ? Xs[xrow[i] + s] : 1.0f;
            union { s8v v; unsigned u[4]; } U;
            #pragma unroll
            for (int e = 0; e < 4; ++e) {
                __hip_bfloat162 h = __float22bfloat162_rn(
                    make_float2(xs * xk[i][2 * e], xs * xk[i][2 * e + 1]));
                U.u[e] = *reinterpret_cast<unsigned*>(&h);
            }
            af[i] = U.v;
        }

        // B-fragments + MFMA
        s8v bf[8];
        #pragma unroll
        for (int j = 0; j < 8; ++j)
            bf[j] = *(const s8v*)&Bb[buf][(wc * 8 + j) * 512 + lane * 8];
        #pragma unroll
        for (int i = 0; i < 4; ++i)
            #pragma unroll
            for (int j = 0; j < 8; ++j)
                acc[i][j] = __builtin_amdgcn_mfma_f32_16x16x32_bf16(
                    af[i], bf[j], acc[i][j], 0, 0, 0);

        __syncthreads();   // reads of buf done everywhere; buf^1 writes landed
        buf ^= 1;
    }

    // ---- epilogue: weighted LSE over this wave's 128 clusters
    float cstr[8];
    #pragma unroll
    for (int j = 0; j < 8; ++j)
        cstr[j] = cst_s[wc * 128 + j * 16 + r];

    float mx[16], sm[16];
    #pragma unroll
    for (int i = 0; i < 4; ++i)
        #pragma unroll
        for (int rg = 0; rg < 4; ++rg) {
            const int sl = i * 4 + rg;
            float m_ = -1e30f;
            #pragma unroll
            for (int j = 0; j < 8; ++j)
                m_ = fmaxf(m_, fmaf(acc[i][j][rg], -0.5f, cstr[j]));
            float s_ = 0.f;
            #pragma unroll
            for (int j = 0; j < 8; ++j)
                s_ += __expf(fmaf(acc[i][j][rg], -0.5f, cstr[j]) - m_);
            mx[sl] = m_; sm[sl] = s_;
        }

    // butterfly over the 16 col-lanes
    #pragma unroll
    for (int d = 1; d < 16; d <<= 1) {
        #pragma unroll
        for (int sl = 0; sl < 16; ++sl) {
            const float pm = __shfl_xor(mx[sl], d, 64);
            const float ps = __shfl_xor(sm[sl], d, 64);
            const float nm = fmaxf(mx[sl], pm);
            sm[sl] = sm[sl] * __expf(mx[sl] - nm) + ps * __expf(pm - nm);
            mx[sl] = nm;
        }
    }

    // cross col-group merge via LDS
    if (wc == 0 && r == 0) {
        #pragma unroll
        for (int i = 0; i < 4; ++i)
            #pragma unroll
            for (int rg = 0; rg < 4; ++rg) {
                const int p2 = wr * 64 + i * 16 + kg * 4 + rg;
                lse_m[p2] = mx[i * 4 + rg];
                lse_d[p2] = sm[i * 4 + rg];
            }
    }
    __syncthreads();
    if (wc == 1 && r == 0) {
        const float thrv = thr[0];
        #pragma unroll
        for (int i = 0; i < 4; ++i)
            #pragma unroll
            for (int rg = 0; rg < 4; ++rg) {
                const int sl = i * 4 + rg;
                const int p2 = wr * 64 + i * 16 + kg * 4 + rg;
                const float om = lse_m[p2], os = lse_d[p2];
                const float nm = fmaxf(mx[sl], om);
                const float ss = sm[sl] * __expf(mx[sl] - nm) + os * __expf(om - nm);
                out[P0 + p2] = nm + __logf(ss) - 0.5f * nrm_s[p2] - thrv;
            }
    }
}

extern "C" void kernel_launch(void* const* d_in, const int* in_sizes, int n_in,
                              void* d_out, int out_size, void* d_ws, size_t ws_size,
                              hipStream_t stream)
{
    const float* X      = (const float*)d_in[0];
    const float* center = (const float*)d_in[1];
    const float* L      = (const float*)d_in[2];
    const float* weight = (const float*)d_in[3];
    const float* thr    = (const float*)d_in[4];
    float* out = (float*)d_out;

    // ws layout: cst [256] f32 | G [33*8192] bf16-as-short
    float* cst = (float*)d_ws;
    short* G   = (short*)((char*)d_ws + 1024);

    gmm_prep<<<MCL, 64, 0, stream>>>(center, L, weight, G, cst);
    gmm_mfma<<<NPTS / BPTS, THREADS, 0, stream>>>(X, G, cst, thr, out);
}